// Round 1
// baseline (64924.695 us; speedup 1.0000x reference)
//
#include <hip/hip_runtime.h>
#include <math.h>

// Problem constants (fixed by the reference)
#define N_NODES 16384
#define HID 512
#define G4 2048   // 4*HID
#define G3 1536   // 3*HID
#define MAXC 4

// Dataflow kernel config: T teams of S workgroups, 256 threads each.
// grid = T*S = 256 == #CUs -> all workgroups co-resident, claim order = index
// order -> deadlock-free.
#define T_TEAMS 16
#define S_WGS 16
#define NWG (T_TEAMS * S_WGS)
#define SLICE (HID / S_WGS)   // 32 hidden dims per wg
#define NSUB (256 / SLICE)    // 8 e-range sub-chunks
#define ELEN (HID / NSUB)     // 64 e's per sub-chunk

__device__ __forceinline__ float sigm(float x) { return 1.0f / (1.0f + __expf(-x)); }

// ---------------------------------------------------------------------------
// Kernel 1: i2h = inputs @ i2h_weight^T + i2h_bias   (16384x512 * 2048x512^T)
// fp32, 64x64 tile, BK=16, 256 threads, thread computes 4x4 via float4 LDS.
// ---------------------------------------------------------------------------
#define BK 16
__global__ void __launch_bounds__(256) gemm_i2h(
    const float* __restrict__ A, const float* __restrict__ B,
    const float* __restrict__ bias, float* __restrict__ C)
{
  __shared__ float As[BK][68];
  __shared__ float Bs[BK][68];
  const int tid = threadIdx.x;
  const int tx = tid & 15, ty = tid >> 4;
  const int rowBase = blockIdx.y * 64, colBase = blockIdx.x * 64;
  const int r = tid >> 2;            // 0..63
  const int kk = (tid & 3) << 2;     // 0,4,8,12
  float acc[4][4] = {};

  for (int k0 = 0; k0 < 512; k0 += BK) {
    float4 a4 = *(const float4*)&A[(size_t)(rowBase + r) * 512 + k0 + kk];
    float4 b4 = *(const float4*)&B[(size_t)(colBase + r) * 512 + k0 + kk];
    __syncthreads();  // protect previous iteration's LDS reads
    As[kk + 0][r] = a4.x; As[kk + 1][r] = a4.y; As[kk + 2][r] = a4.z; As[kk + 3][r] = a4.w;
    Bs[kk + 0][r] = b4.x; Bs[kk + 1][r] = b4.y; Bs[kk + 2][r] = b4.z; Bs[kk + 3][r] = b4.w;
    __syncthreads();
#pragma unroll
    for (int k = 0; k < BK; k++) {
      float4 av = *(const float4*)&As[k][ty << 2];
      float4 bv = *(const float4*)&Bs[k][tx << 2];
      float a0 = av.x, a1 = av.y, a2 = av.z, a3 = av.w;
      float b0 = bv.x, b1 = bv.y, b2 = bv.z, b3 = bv.w;
      acc[0][0] += a0 * b0; acc[0][1] += a0 * b1; acc[0][2] += a0 * b2; acc[0][3] += a0 * b3;
      acc[1][0] += a1 * b0; acc[1][1] += a1 * b1; acc[1][2] += a1 * b2; acc[1][3] += a1 * b3;
      acc[2][0] += a2 * b0; acc[2][1] += a2 * b1; acc[2][2] += a2 * b2; acc[2][3] += a2 * b3;
      acc[3][0] += a3 * b0; acc[3][1] += a3 * b1; acc[3][2] += a3 * b2; acc[3][3] += a3 * b3;
    }
  }
#pragma unroll
  for (int i = 0; i < 4; i++) {
    const int row = rowBase + (ty << 2) + i;
    const int col = colBase + (tx << 2);
    float4 o;
    o.x = acc[i][0] + bias[col + 0];
    o.y = acc[i][1] + bias[col + 1];
    o.z = acc[i][2] + bias[col + 2];
    o.w = acc[i][3] + bias[col + 3];
    *(float4*)&C[(size_t)row * G4 + col] = o;
  }
}

// ---------------------------------------------------------------------------
// Kernel 2: build WT[e][r], e in [0,512), r in [0,2048):
//   r <  1536 : hs2h_weight[r][e]   (so y[r] = sum_e WT[e][r]*hs[e])
//   r >= 1536 : hc2h_weight[e][r-1536] (so z[q] = sum_e WT[e][1536+q]*h[e])
// ---------------------------------------------------------------------------
__global__ void __launch_bounds__(256) make_wt(
    const float* __restrict__ hs2h_w, const float* __restrict__ hc2h_w,
    float* __restrict__ WT)
{
  const int idx = blockIdx.x * 256 + threadIdx.x;  // over 512*2048
  const int e = idx >> 11, rcol = idx & 2047;
  WT[idx] = (rcol < G3) ? hs2h_w[rcol * HID + e] : hc2h_w[e * HID + (rcol - G3)];
}

// ---------------------------------------------------------------------------
// Kernel 3: persistent dataflow recurrence.
// Team t processes nodes t, t+T, ... in order; its S wgs each own a 32-wide
// hidden slice. Readiness: cnt[j] == S_WGS (agent-scope release fetch_add).
// ---------------------------------------------------------------------------
__global__ void __launch_bounds__(256) recur(
    const float* __restrict__ i2h, const float* __restrict__ WT,
    const float* __restrict__ hs2h_b, const float* __restrict__ hc2h_b,
    const int* __restrict__ child_idx, const int* __restrict__ child_mask,
    float* __restrict__ Hout, float* __restrict__ Cout, int* cnt)
{
  __shared__ float hch[MAXC][HID];           // children h
  __shared__ float hs[HID];                  // masked child-sum of h
  __shared__ float red[7][NSUB][SLICE];      // partial-dot reduction

  const int tid = threadIdx.x;
  const int wg = blockIdx.x;
  const int team = wg & (T_TEAMS - 1);
  const int slice = wg / T_TEAMS;            // 0..15
  const int rr = tid & (SLICE - 1);          // 0..31
  const int sub = tid / SLICE;               // 0..7
  const int rp = slice * SLICE + rr;         // this thread's hidden dim

  for (int j = team; j < N_NODES; j += T_TEAMS) {
    const int4 ci = *(const int4*)&child_idx[j * 4];
    const int4 cm = *(const int4*)&child_mask[j * 4];
    const int nc = cm.x + cm.y + cm.z + cm.w;  // mask is a prefix
    int ck[MAXC] = {ci.x, ci.y, ci.z, ci.w};

    float accI = 0.f, accU = 0.f, accO = 0.f;
    float accF[MAXC] = {0.f, 0.f, 0.f, 0.f};

    if (nc > 0) {
      // wait for all children (all threads poll; relaxed spin + final acquire)
      for (int k = 0; k < nc; k++) {
        int* cp = cnt + ck[k];
        while (__hip_atomic_load(cp, __ATOMIC_RELAXED, __HIP_MEMORY_SCOPE_AGENT) != S_WGS)
          __builtin_amdgcn_s_sleep(1);
        (void)__hip_atomic_load(cp, __ATOMIC_ACQUIRE, __HIP_MEMORY_SCOPE_AGENT);
      }
      __syncthreads();  // B1: prior-node LDS use finished before overwrite
      for (int k = 0; k < nc; k++) {
        const float* hsrc = Hout + (size_t)ck[k] * HID;
        for (int e = tid; e < HID; e += 256) hch[k][e] = hsrc[e];
      }
      __syncthreads();  // B2
      for (int e = tid; e < HID; e += 256) {
        float s = hch[0][e];
        for (int k = 1; k < nc; k++) s += hch[k][e];
        hs[e] = s;
      }
      __syncthreads();  // B3

      const int e0 = sub * ELEN;
      const float* wbase = WT + (size_t)e0 * G4;
#pragma unroll 4
      for (int e = 0; e < ELEN; e++) {
        const float* w = wbase + (size_t)e * G4;
        const float hse = hs[e0 + e];
        accI += w[rp] * hse;
        accU += w[512 + rp] * hse;
        accO += w[1024 + rp] * hse;
        const float wf = w[1536 + rp];
#pragma unroll
        for (int k = 0; k < MAXC; k++)
          if (k < nc) accF[k] += wf * hch[k][e0 + e];
      }
      red[0][sub][rr] = accI; red[1][sub][rr] = accU; red[2][sub][rr] = accO;
      red[3][sub][rr] = accF[0]; red[4][sub][rr] = accF[1];
      red[5][sub][rr] = accF[2]; red[6][sub][rr] = accF[3];
      __syncthreads();  // B4
    }

    if (tid < SLICE) {
      float aI = 0.f, aU = 0.f, aO = 0.f, aF[MAXC] = {0.f, 0.f, 0.f, 0.f};
      if (nc > 0) {
#pragma unroll
        for (int s = 0; s < NSUB; s++) {
          aI += red[0][s][tid]; aU += red[1][s][tid]; aO += red[2][s][tid];
          aF[0] += red[3][s][tid]; aF[1] += red[4][s][tid];
          aF[2] += red[5][s][tid]; aF[3] += red[6][s][tid];
        }
      }
      const int rpp = slice * SLICE + tid;
      const size_t jb = (size_t)j * G4;
      const float ipre = i2h[jb + rpp];
      const float fpre = i2h[jb + 512 + rpp];
      const float upre = i2h[jb + 1024 + rpp];
      const float opre = i2h[jb + 1536 + rpp];
      const float ig = ipre + hs2h_b[rpp] + aI;
      const float ug = upre + hs2h_b[512 + rpp] + aU;
      const float og = opre + hs2h_b[1024 + rpp] + aO;
      float c = sigm(ig) * tanhf(ug);
#pragma unroll
      for (int k = 0; k < MAXC; k++)
        if (k < nc) {
          const float fk = sigm(fpre + hc2h_b[rpp] + aF[k]);
          c += fk * Cout[(size_t)ck[k] * HID + rpp];
        }
      const float h = sigm(og) * tanhf(c);
      Hout[(size_t)j * HID + rpp] = h;
      Cout[(size_t)j * HID + rpp] = c;
    }
    __syncthreads();  // B5: slice writes done before publishing
    if (tid == 0)
      __hip_atomic_fetch_add(cnt + j, 1, __ATOMIC_RELEASE, __HIP_MEMORY_SCOPE_AGENT);
  }
}

// ---------------------------------------------------------------------------
// Workspace layout (needs ~132.1 MB):
//   [0, 128MB)        i2h   : N x 2048 fp32
//   [128MB, 132MB)    WT    : 512 x 2048 fp32
//   [132MB, +64KB)    cnt   : N int32 ready-counters (zeroed per launch)
// ---------------------------------------------------------------------------
extern "C" void kernel_launch(void* const* d_in, const int* in_sizes, int n_in,
                              void* d_out, int out_size, void* d_ws, size_t ws_size,
                              hipStream_t stream) {
  const float* inputs    = (const float*)d_in[0];
  const float* i2h_w     = (const float*)d_in[1];
  const float* i2h_b     = (const float*)d_in[2];
  const float* hs2h_w    = (const float*)d_in[3];
  const float* hs2h_b    = (const float*)d_in[4];
  const float* hc2h_w    = (const float*)d_in[5];
  const float* hc2h_b    = (const float*)d_in[6];
  const int*   child_idx = (const int*)d_in[7];
  const int*   child_mask= (const int*)d_in[8];

  float* Hout = (float*)d_out;
  float* Cout = Hout + (size_t)N_NODES * HID;

  char* ws = (char*)d_ws;
  const size_t i2h_bytes = (size_t)N_NODES * G4 * sizeof(float);
  const size_t wt_bytes  = (size_t)HID * G4 * sizeof(float);
  float* i2h = (float*)ws;
  float* WT  = (float*)(ws + i2h_bytes);
  int*   cnt = (int*)(ws + i2h_bytes + wt_bytes);

  hipMemsetAsync(cnt, 0, N_NODES * sizeof(int), stream);

  dim3 ggrid(G4 / 64, N_NODES / 64);
  gemm_i2h<<<ggrid, 256, 0, stream>>>(inputs, i2h_w, i2h_b, i2h);
  make_wt<<<(HID * G4) / 256, 256, 0, stream>>>(hs2h_w, hc2h_w, WT);
  recur<<<NWG, 256, 0, stream>>>(i2h, WT, hs2h_b, hc2h_b,
                                 child_idx, child_mask, Hout, Cout, cnt);
}

// Round 2
// 15428.717 us; speedup vs baseline: 4.2080x; 4.2080x over previous
//
#include <hip/hip_runtime.h>
#include <math.h>

// Problem constants (fixed by the reference)
#define N_NODES 16384
#define HID 512
#define G4 2048   // 4*HID
#define MAXC 4

// Dataflow config: 16 teams x 16 wgs, 512 threads each. grid = 256 == #CUs
// -> all workgroups co-resident; teams claim nodes in increasing index order
// -> smallest-unfinished-node argument gives deadlock freedom.
#define T_TEAMS 16
#define S_WGS 16
#define NWG 256
#define BLK 512            // threads per wg (8 waves)
#define NSUB 16            // e-chunks per wg
#define ECH 32             // e's per chunk  (NSUB*ECH = 512)

__device__ __forceinline__ float sigm(float x) { return 1.0f / (1.0f + __expf(-x)); }

// ---------------------------------------------------------------------------
// Kernel 1: i2h = inputs @ i2h_weight^T + i2h_bias   (16384x512 * 2048x512^T)
// fp32, 64x64 tile, BK=16, 256 threads. (unchanged from round 1 — passed)
// ---------------------------------------------------------------------------
#define BK 16
__global__ void __launch_bounds__(256) gemm_i2h(
    const float* __restrict__ A, const float* __restrict__ B,
    const float* __restrict__ bias, float* __restrict__ C)
{
  __shared__ float As[BK][68];
  __shared__ float Bs[BK][68];
  const int tid = threadIdx.x;
  const int tx = tid & 15, ty = tid >> 4;
  const int rowBase = blockIdx.y * 64, colBase = blockIdx.x * 64;
  const int r = tid >> 2;            // 0..63
  const int kk = (tid & 3) << 2;     // 0,4,8,12
  float acc[4][4] = {};

  for (int k0 = 0; k0 < 512; k0 += BK) {
    float4 a4 = *(const float4*)&A[(size_t)(rowBase + r) * 512 + k0 + kk];
    float4 b4 = *(const float4*)&B[(size_t)(colBase + r) * 512 + k0 + kk];
    __syncthreads();  // protect previous iteration's LDS reads
    As[kk + 0][r] = a4.x; As[kk + 1][r] = a4.y; As[kk + 2][r] = a4.z; As[kk + 3][r] = a4.w;
    Bs[kk + 0][r] = b4.x; Bs[kk + 1][r] = b4.y; Bs[kk + 2][r] = b4.z; Bs[kk + 3][r] = b4.w;
    __syncthreads();
#pragma unroll
    for (int k = 0; k < BK; k++) {
      float4 av = *(const float4*)&As[k][ty << 2];
      float4 bv = *(const float4*)&Bs[k][tx << 2];
      float a0 = av.x, a1 = av.y, a2 = av.z, a3 = av.w;
      float b0 = bv.x, b1 = bv.y, b2 = bv.z, b3 = bv.w;
      acc[0][0] += a0 * b0; acc[0][1] += a0 * b1; acc[0][2] += a0 * b2; acc[0][3] += a0 * b3;
      acc[1][0] += a1 * b0; acc[1][1] += a1 * b1; acc[1][2] += a1 * b2; acc[1][3] += a1 * b3;
      acc[2][0] += a2 * b0; acc[2][1] += a2 * b1; acc[2][2] += a2 * b2; acc[2][3] += a2 * b3;
      acc[3][0] += a3 * b0; acc[3][1] += a3 * b1; acc[3][2] += a3 * b2; acc[3][3] += a3 * b3;
    }
  }
#pragma unroll
  for (int i = 0; i < 4; i++) {
    const int row = rowBase + (ty << 2) + i;
    const int col = colBase + (tx << 2);
    float4 o;
    o.x = acc[i][0] + bias[col + 0];
    o.y = acc[i][1] + bias[col + 1];
    o.z = acc[i][2] + bias[col + 2];
    o.w = acc[i][3] + bias[col + 3];
    *(float4*)&C[(size_t)row * G4 + col] = o;
  }
}

// ---------------------------------------------------------------------------
// Per-node gate dot-products, weights in registers, child h streamed from
// global (L1-broadcast: all lanes of a half-wave read the same float4).
// Child-sum hs computed on the fly. NC templated -> uniform branch, no
// wasted FMAs, no NaN hazards from absent children.
// ---------------------------------------------------------------------------
template<int NC>
__device__ __forceinline__ void gates(
    const float* __restrict__ h0p, const float* __restrict__ h1p,
    const float* __restrict__ h2p, const float* __restrict__ h3p,
    const float4* wi, const float4* wu, const float4* wo, const float* wf,
    float& aI, float& aU, float& aO, float (&aF)[4])
{
#pragma unroll
  for (int q = 0; q < 8; q++) {
    float4 c0 = *(const float4*)(h0p + 4 * q);
    float4 c1 = {0.f, 0.f, 0.f, 0.f}, c2 = {0.f, 0.f, 0.f, 0.f}, c3 = {0.f, 0.f, 0.f, 0.f};
    if constexpr (NC > 1) c1 = *(const float4*)(h1p + 4 * q);
    if constexpr (NC > 2) c2 = *(const float4*)(h2p + 4 * q);
    if constexpr (NC > 3) c3 = *(const float4*)(h3p + 4 * q);
    float sx = c0.x, sy = c0.y, sz = c0.z, sw = c0.w;
    if constexpr (NC > 1) { sx += c1.x; sy += c1.y; sz += c1.z; sw += c1.w; }
    if constexpr (NC > 2) { sx += c2.x; sy += c2.y; sz += c2.z; sw += c2.w; }
    if constexpr (NC > 3) { sx += c3.x; sy += c3.y; sz += c3.z; sw += c3.w; }
    aI += wi[q].x * sx; aI += wi[q].y * sy; aI += wi[q].z * sz; aI += wi[q].w * sw;
    aU += wu[q].x * sx; aU += wu[q].y * sy; aU += wu[q].z * sz; aU += wu[q].w * sw;
    aO += wo[q].x * sx; aO += wo[q].y * sy; aO += wo[q].z * sz; aO += wo[q].w * sw;
    aF[0] += wf[4*q+0] * c0.x; aF[0] += wf[4*q+1] * c0.y;
    aF[0] += wf[4*q+2] * c0.z; aF[0] += wf[4*q+3] * c0.w;
    if constexpr (NC > 1) {
      aF[1] += wf[4*q+0] * c1.x; aF[1] += wf[4*q+1] * c1.y;
      aF[1] += wf[4*q+2] * c1.z; aF[1] += wf[4*q+3] * c1.w;
    }
    if constexpr (NC > 2) {
      aF[2] += wf[4*q+0] * c2.x; aF[2] += wf[4*q+1] * c2.y;
      aF[2] += wf[4*q+2] * c2.z; aF[2] += wf[4*q+3] * c2.w;
    }
    if constexpr (NC > 3) {
      aF[3] += wf[4*q+0] * c3.x; aF[3] += wf[4*q+1] * c3.y;
      aF[3] += wf[4*q+2] * c3.z; aF[3] += wf[4*q+3] * c3.w;
    }
  }
}

// ---------------------------------------------------------------------------
// Kernel 2: persistent dataflow recurrence, weights register-resident.
// Only tid==0 polls (relaxed) + one acquire per node; L1/L2 are CU/XCD-shared
// so one acquire-invalidate covers every wave's subsequent child reads.
// Release fetch_add's vmcnt(0) drain orders wave0's H/C stores -> no publish
// barrier needed. 2 barriers per non-leaf node, 0 per leaf.
// ---------------------------------------------------------------------------
__global__ void __launch_bounds__(BLK, 2) recur(
    const float* __restrict__ i2h,
    const float* __restrict__ hs2h_w, const float* __restrict__ hc2h_w,
    const float* __restrict__ hs2h_b, const float* __restrict__ hc2h_b,
    const int* __restrict__ child_idx, const int* __restrict__ child_mask,
    float* __restrict__ Hout, float* __restrict__ Cout, int* cnt)
{
  __shared__ float red[7][NSUB][32];   // 14 KB

  const int tid = threadIdx.x;
  const int wg = blockIdx.x;
  const int team = wg & (T_TEAMS - 1);
  const int slice = wg >> 4;           // 0..15 : this wg's 32 hidden dims
  const int rr = tid & 31;             // r within slice
  const int sub = tid >> 5;            // 0..15 : e-chunk
  const int rp = slice * 32 + rr;      // hidden dim for dot-products
  const int e0 = sub * ECH;            // e-range start

  // ---- one-time: weights into registers (128 floats/thread) ----
  float4 wi[8], wu[8], wo[8];
  float wf[32];
#pragma unroll
  for (int q = 0; q < 8; q++) {
    wi[q] = *(const float4*)&hs2h_w[(size_t)rp * HID + e0 + 4 * q];
    wu[q] = *(const float4*)&hs2h_w[(size_t)(512 + rp) * HID + e0 + 4 * q];
    wo[q] = *(const float4*)&hs2h_w[(size_t)(1024 + rp) * HID + e0 + 4 * q];
  }
#pragma unroll
  for (int e = 0; e < 32; e++)
    wf[e] = hc2h_w[(size_t)(e0 + e) * HID + rp];

  // ---- one-time: epilogue biases (wave0 / tid<32 only) ----
  const int rpp = slice * 32 + tid;    // valid only for tid<32
  float bI = 0.f, bU = 0.f, bO = 0.f, bF = 0.f;
  if (tid < 32) {
    bI = hs2h_b[rpp]; bU = hs2h_b[512 + rpp];
    bO = hs2h_b[1024 + rpp]; bF = hc2h_b[rpp];
  }

  for (int j = team; j < N_NODES; j += T_TEAMS) {
    const int4 ci = *(const int4*)&child_idx[j * 4];
    const int4 cm = *(const int4*)&child_mask[j * 4];
    const int nc = cm.x + cm.y + cm.z + cm.w;   // mask is a prefix

    // prefetch i2h (independent of children; overlaps the wait)
    float ipre = 0.f, fpre = 0.f, upre = 0.f, opre = 0.f;
    if (tid < 32) {
      const size_t jb = (size_t)j * G4;
      ipre = i2h[jb + rpp];
      fpre = i2h[jb + 512 + rpp];
      upre = i2h[jb + 1024 + rpp];
      opre = i2h[jb + 1536 + rpp];
    }

    float aI = 0.f, aU = 0.f, aO = 0.f, aF[4] = {0.f, 0.f, 0.f, 0.f};

    if (nc > 0) {
      if (tid == 0) {
        // relaxed spin per child, single poller per wg
        while (__hip_atomic_load(cnt + ci.x, __ATOMIC_RELAXED, __HIP_MEMORY_SCOPE_AGENT) != S_WGS)
          __builtin_amdgcn_s_sleep(1);
        if (nc > 1)
          while (__hip_atomic_load(cnt + ci.y, __ATOMIC_RELAXED, __HIP_MEMORY_SCOPE_AGENT) != S_WGS)
            __builtin_amdgcn_s_sleep(1);
        if (nc > 2)
          while (__hip_atomic_load(cnt + ci.z, __ATOMIC_RELAXED, __HIP_MEMORY_SCOPE_AGENT) != S_WGS)
            __builtin_amdgcn_s_sleep(1);
        if (nc > 3)
          while (__hip_atomic_load(cnt + ci.w, __ATOMIC_RELAXED, __HIP_MEMORY_SCOPE_AGENT) != S_WGS)
            __builtin_amdgcn_s_sleep(1);
        // one acquire: invalidates L1 (per-CU) + L2 (per-XCD) for all waves
        (void)__hip_atomic_load(cnt + ci.x, __ATOMIC_ACQUIRE, __HIP_MEMORY_SCOPE_AGENT);
      }
      __syncthreads();  // B1: broadcast readiness + order acquire before reads

      const float* hb0 = Hout + (size_t)ci.x * HID + e0;
      const float* hb1 = (nc > 1) ? Hout + (size_t)ci.y * HID + e0 : hb0;
      const float* hb2 = (nc > 2) ? Hout + (size_t)ci.z * HID + e0 : hb0;
      const float* hb3 = (nc > 3) ? Hout + (size_t)ci.w * HID + e0 : hb0;
      switch (nc) {
        case 1: gates<1>(hb0, hb1, hb2, hb3, wi, wu, wo, wf, aI, aU, aO, aF); break;
        case 2: gates<2>(hb0, hb1, hb2, hb3, wi, wu, wo, wf, aI, aU, aO, aF); break;
        case 3: gates<3>(hb0, hb1, hb2, hb3, wi, wu, wo, wf, aI, aU, aO, aF); break;
        default: gates<4>(hb0, hb1, hb2, hb3, wi, wu, wo, wf, aI, aU, aO, aF); break;
      }
      red[0][sub][rr] = aI;    red[1][sub][rr] = aU;    red[2][sub][rr] = aO;
      red[3][sub][rr] = aF[0]; red[4][sub][rr] = aF[1];
      red[5][sub][rr] = aF[2]; red[6][sub][rr] = aF[3];
      __syncthreads();  // B4: red ready for epilogue
    }

    if (tid < 32) {
      float sI = 0.f, sU = 0.f, sO = 0.f;
      float sF0 = 0.f, sF1 = 0.f, sF2 = 0.f, sF3 = 0.f;
      if (nc > 0) {
#pragma unroll
        for (int s = 0; s < NSUB; s++) {
          sI += red[0][s][tid]; sU += red[1][s][tid]; sO += red[2][s][tid];
          sF0 += red[3][s][tid]; sF1 += red[4][s][tid];
          sF2 += red[5][s][tid]; sF3 += red[6][s][tid];
        }
      }
      const float ig = ipre + bI + sI;
      const float ug = upre + bU + sU;
      const float og = opre + bO + sO;
      float c = sigm(ig) * tanhf(ug);
      if (nc > 0) c += sigm(fpre + bF + sF0) * Cout[(size_t)ci.x * HID + rpp];
      if (nc > 1) c += sigm(fpre + bF + sF1) * Cout[(size_t)ci.y * HID + rpp];
      if (nc > 2) c += sigm(fpre + bF + sF2) * Cout[(size_t)ci.z * HID + rpp];
      if (nc > 3) c += sigm(fpre + bF + sF3) * Cout[(size_t)ci.w * HID + rpp];
      const float h = sigm(og) * tanhf(c);
      Hout[(size_t)j * HID + rpp] = h;
      Cout[(size_t)j * HID + rpp] = c;
    }
    // release: waits wave0's own vmcnt(0) (drains the H/C stores above),
    // writes back XCD L2 to the coherence point, then bumps the counter.
    if (tid == 0)
      __hip_atomic_fetch_add(cnt + j, 1, __ATOMIC_RELEASE, __HIP_MEMORY_SCOPE_AGENT);
  }
}

// ---------------------------------------------------------------------------
// Workspace: [0,128MB) i2h ; [128MB, +64KB) cnt
// ---------------------------------------------------------------------------
extern "C" void kernel_launch(void* const* d_in, const int* in_sizes, int n_in,
                              void* d_out, int out_size, void* d_ws, size_t ws_size,
                              hipStream_t stream) {
  const float* inputs    = (const float*)d_in[0];
  const float* i2h_w     = (const float*)d_in[1];
  const float* i2h_b     = (const float*)d_in[2];
  const float* hs2h_w    = (const float*)d_in[3];
  const float* hs2h_b    = (const float*)d_in[4];
  const float* hc2h_w    = (const float*)d_in[5];
  const float* hc2h_b    = (const float*)d_in[6];
  const int*   child_idx = (const int*)d_in[7];
  const int*   child_mask= (const int*)d_in[8];

  float* Hout = (float*)d_out;
  float* Cout = Hout + (size_t)N_NODES * HID;

  char* ws = (char*)d_ws;
  const size_t i2h_bytes = (size_t)N_NODES * G4 * sizeof(float);
  float* i2h = (float*)ws;
  int*   cnt = (int*)(ws + i2h_bytes);

  hipMemsetAsync(cnt, 0, N_NODES * sizeof(int), stream);

  dim3 ggrid(G4 / 64, N_NODES / 64);
  gemm_i2h<<<ggrid, 256, 0, stream>>>(inputs, i2h_w, i2h_b, i2h);
  recur<<<NWG, BLK, 0, stream>>>(i2h, hs2h_w, hc2h_w, hs2h_b, hc2h_b,
                                 child_idx, child_mask, Hout, Cout, cnt);
}

// Round 3
// 8306.496 us; speedup vs baseline: 7.8161x; 1.8574x over previous
//
#include <hip/hip_runtime.h>
#include <math.h>

// Problem constants (fixed by the reference)
#define N_NODES 16384
#define HID 512
#define G4 2048   // 4*HID
#define MAXC 4

// Dataflow config: 16 teams x 16 slices (wgs), 512 threads each. grid = 256
// == #CUs -> all wgs co-resident; teams claim nodes in increasing index order
// -> smallest-unfinished-node argument gives deadlock freedom.
#define T_TEAMS 16
#define S_WGS 16
#define NWG 256
#define BLK 512            // threads per wg (8 waves)
#define NSUB 16            // e-chunks per wg
#define ECH 32             // e's per chunk  (NSUB*ECH = 512)
#define FPN 16             // flag words per node (one per slice, one 64B line)

#define AT_LD(p)    __hip_atomic_load((p), __ATOMIC_RELAXED, __HIP_MEMORY_SCOPE_AGENT)
#define AT_ST(p, v) __hip_atomic_store((p), (v), __ATOMIC_RELAXED, __HIP_MEMORY_SCOPE_AGENT)

__device__ __forceinline__ float sigm(float x) { return 1.0f / (1.0f + __expf(-x)); }

// ---------------------------------------------------------------------------
// Kernel 1: i2h = inputs @ i2h_weight^T + i2h_bias (unchanged — correct)
// ---------------------------------------------------------------------------
#define BK 16
__global__ void __launch_bounds__(256) gemm_i2h(
    const float* __restrict__ A, const float* __restrict__ B,
    const float* __restrict__ bias, float* __restrict__ C)
{
  __shared__ float As[BK][68];
  __shared__ float Bs[BK][68];
  const int tid = threadIdx.x;
  const int tx = tid & 15, ty = tid >> 4;
  const int rowBase = blockIdx.y * 64, colBase = blockIdx.x * 64;
  const int r = tid >> 2;
  const int kk = (tid & 3) << 2;
  float acc[4][4] = {};

  for (int k0 = 0; k0 < 512; k0 += BK) {
    float4 a4 = *(const float4*)&A[(size_t)(rowBase + r) * 512 + k0 + kk];
    float4 b4 = *(const float4*)&B[(size_t)(colBase + r) * 512 + k0 + kk];
    __syncthreads();
    As[kk + 0][r] = a4.x; As[kk + 1][r] = a4.y; As[kk + 2][r] = a4.z; As[kk + 3][r] = a4.w;
    Bs[kk + 0][r] = b4.x; Bs[kk + 1][r] = b4.y; Bs[kk + 2][r] = b4.z; Bs[kk + 3][r] = b4.w;
    __syncthreads();
#pragma unroll
    for (int k = 0; k < BK; k++) {
      float4 av = *(const float4*)&As[k][ty << 2];
      float4 bv = *(const float4*)&Bs[k][tx << 2];
      float a0 = av.x, a1 = av.y, a2 = av.z, a3 = av.w;
      float b0 = bv.x, b1 = bv.y, b2 = bv.z, b3 = bv.w;
      acc[0][0] += a0 * b0; acc[0][1] += a0 * b1; acc[0][2] += a0 * b2; acc[0][3] += a0 * b3;
      acc[1][0] += a1 * b0; acc[1][1] += a1 * b1; acc[1][2] += a1 * b2; acc[1][3] += a1 * b3;
      acc[2][0] += a2 * b0; acc[2][1] += a2 * b1; acc[2][2] += a2 * b2; acc[2][3] += a2 * b3;
      acc[3][0] += a3 * b0; acc[3][1] += a3 * b1; acc[3][2] += a3 * b2; acc[3][3] += a3 * b3;
    }
  }
#pragma unroll
  for (int i = 0; i < 4; i++) {
    const int row = rowBase + (ty << 2) + i;
    const int col = colBase + (tx << 2);
    float4 o;
    o.x = acc[i][0] + bias[col + 0];
    o.y = acc[i][1] + bias[col + 1];
    o.z = acc[i][2] + bias[col + 2];
    o.w = acc[i][3] + bias[col + 3];
    *(float4*)&C[(size_t)row * G4 + col] = o;
  }
}

// ---------------------------------------------------------------------------
// Gate dot-products: weights in registers, child h from LDS (broadcast reads).
// ---------------------------------------------------------------------------
template<int NC>
__device__ __forceinline__ void gates_lds(
    const float (*hch)[HID], int e0,
    const float4* wi, const float4* wu, const float4* wo, const float* wf,
    float& aI, float& aU, float& aO, float (&aF)[4])
{
#pragma unroll
  for (int q = 0; q < 8; q++) {
    float4 c0 = *(const float4*)&hch[0][e0 + 4 * q];
    float4 c1 = {0,0,0,0}, c2 = {0,0,0,0}, c3 = {0,0,0,0};
    if constexpr (NC > 1) c1 = *(const float4*)&hch[1][e0 + 4 * q];
    if constexpr (NC > 2) c2 = *(const float4*)&hch[2][e0 + 4 * q];
    if constexpr (NC > 3) c3 = *(const float4*)&hch[3][e0 + 4 * q];
    float sx = c0.x, sy = c0.y, sz = c0.z, sw = c0.w;
    if constexpr (NC > 1) { sx += c1.x; sy += c1.y; sz += c1.z; sw += c1.w; }
    if constexpr (NC > 2) { sx += c2.x; sy += c2.y; sz += c2.z; sw += c2.w; }
    if constexpr (NC > 3) { sx += c3.x; sy += c3.y; sz += c3.z; sw += c3.w; }
    aI += wi[q].x * sx; aI += wi[q].y * sy; aI += wi[q].z * sz; aI += wi[q].w * sw;
    aU += wu[q].x * sx; aU += wu[q].y * sy; aU += wu[q].z * sz; aU += wu[q].w * sw;
    aO += wo[q].x * sx; aO += wo[q].y * sy; aO += wo[q].z * sz; aO += wo[q].w * sw;
    aF[0] += wf[4*q+0] * c0.x; aF[0] += wf[4*q+1] * c0.y;
    aF[0] += wf[4*q+2] * c0.z; aF[0] += wf[4*q+3] * c0.w;
    if constexpr (NC > 1) {
      aF[1] += wf[4*q+0] * c1.x; aF[1] += wf[4*q+1] * c1.y;
      aF[1] += wf[4*q+2] * c1.z; aF[1] += wf[4*q+3] * c1.w;
    }
    if constexpr (NC > 2) {
      aF[2] += wf[4*q+0] * c2.x; aF[2] += wf[4*q+1] * c2.y;
      aF[2] += wf[4*q+2] * c2.z; aF[2] += wf[4*q+3] * c2.w;
    }
    if constexpr (NC > 3) {
      aF[3] += wf[4*q+0] * c3.x; aF[3] += wf[4*q+1] * c3.y;
      aF[3] += wf[4*q+2] * c3.z; aF[3] += wf[4*q+3] * c3.w;
    }
  }
}

// ---------------------------------------------------------------------------
// Kernel 2: persistent dataflow recurrence.
// ALL cross-wg traffic (H, C, flags) uses relaxed AGENT-scope atomics — these
// lower to per-access device-coherent loads/stores served at the LLC, with NO
// bulk L1/L2 invalidate/writeback (that was round 2's hidden 8 µs/hop cost).
// Producer order: data stores -> s_waitcnt(0) -> flag store.
// Consumer order: flag poll (one coalesced wave-wide load covering all
// children x all slices) -> barrier -> data loads. No RMW, no fences.
// ---------------------------------------------------------------------------
__global__ void __launch_bounds__(BLK, 2) recur(
    const float* __restrict__ i2h,
    const float* __restrict__ hs2h_w, const float* __restrict__ hc2h_w,
    const float* __restrict__ hs2h_b, const float* __restrict__ hc2h_b,
    const int* __restrict__ child_idx, const int* __restrict__ child_mask,
    float* Hout, float* Cout, int* flags)
{
  __shared__ float hch[MAXC][HID];     // 8 KB: children h
  __shared__ float red[7][NSUB][32];   // 14 KB: partial-dot reduction

  const int tid = threadIdx.x;
  const int wg = blockIdx.x;
  const int team = wg & (T_TEAMS - 1);
  const int slice = wg >> 4;           // 0..15 : this wg's 32 hidden dims
  const int rr = tid & 31;
  const int sub = tid >> 5;            // 0..15 : e-chunk
  const int rp = slice * 32 + rr;
  const int e0 = sub * ECH;

  // ---- one-time: weights into registers (128 floats/thread) ----
  float4 wi[8], wu[8], wo[8];
  float wf[32];
#pragma unroll
  for (int q = 0; q < 8; q++) {
    wi[q] = *(const float4*)&hs2h_w[(size_t)rp * HID + e0 + 4 * q];
    wu[q] = *(const float4*)&hs2h_w[(size_t)(512 + rp) * HID + e0 + 4 * q];
    wo[q] = *(const float4*)&hs2h_w[(size_t)(1024 + rp) * HID + e0 + 4 * q];
  }
#pragma unroll
  for (int e = 0; e < 32; e++)
    wf[e] = hc2h_w[(size_t)(e0 + e) * HID + rp];

  // ---- one-time: epilogue biases (wave0 / tid<32 only) ----
  const int rpp = slice * 32 + tid;    // valid only for tid<32
  float bI = 0.f, bU = 0.f, bO = 0.f, bF = 0.f;
  if (tid < 32) {
    bI = hs2h_b[rpp]; bU = hs2h_b[512 + rpp];
    bO = hs2h_b[1024 + rpp]; bF = hc2h_b[rpp];
  }

  for (int j = team; j < N_NODES; j += T_TEAMS) {
    const int4 ci = *(const int4*)&child_idx[j * 4];
    const int4 cm = *(const int4*)&child_mask[j * 4];
    const int nc = cm.x + cm.y + cm.z + cm.w;   // mask is a prefix
    const int cix[4] = {ci.x, ci.y, ci.z, ci.w};

    // prefetch i2h (normal cached loads; independent of children)
    float ipre = 0.f, fpre = 0.f, upre = 0.f, opre = 0.f;
    if (tid < 32) {
      const size_t jb = (size_t)j * G4;
      ipre = i2h[jb + rpp];
      fpre = i2h[jb + 512 + rpp];
      upre = i2h[jb + 1024 + rpp];
      opre = i2h[jb + 1536 + rpp];
    }

    float aI = 0.f, aU = 0.f, aO = 0.f, aF[4] = {0.f, 0.f, 0.f, 0.f};
    float cC[4] = {0.f, 0.f, 0.f, 0.f};

    if (nc > 0) {
      // ---- readiness: wave0 polls ALL children x ALL slices in one load ----
      if (tid < 64) {
        const int k = tid >> 4, s = tid & 15;
        const int cj = (k < nc) ? cix[k] : cix[0];
        int* fp = flags + cj * FPN + s;
        for (;;) {
          const int v = AT_LD(fp);
          const bool ok = (k >= nc) || (v != 0);
          if (__ballot(ok) == ~0ull) break;
        }
      }
      __syncthreads();  // B1: readiness broadcast (also LDS WAR protection)

      // ---- cooperative child-h stage -> LDS (coalesced LLC loads) ----
#pragma unroll
      for (int k = 0; k < MAXC; k++)
        if (k < nc) hch[k][tid] = AT_LD(Hout + (size_t)cix[k] * HID + tid);
      // wave0: prefetch child C for the epilogue (overlaps gates)
      if (tid < 32) {
#pragma unroll
        for (int k = 0; k < MAXC; k++)
          if (k < nc) cC[k] = AT_LD(Cout + (size_t)cix[k] * HID + rpp);
      }
      __syncthreads();  // B2: hch ready

      switch (nc) {
        case 1: gates_lds<1>(hch, e0, wi, wu, wo, wf, aI, aU, aO, aF); break;
        case 2: gates_lds<2>(hch, e0, wi, wu, wo, wf, aI, aU, aO, aF); break;
        case 3: gates_lds<3>(hch, e0, wi, wu, wo, wf, aI, aU, aO, aF); break;
        default: gates_lds<4>(hch, e0, wi, wu, wo, wf, aI, aU, aO, aF); break;
      }
      red[0][sub][rr] = aI;    red[1][sub][rr] = aU;    red[2][sub][rr] = aO;
      red[3][sub][rr] = aF[0]; red[4][sub][rr] = aF[1];
      red[5][sub][rr] = aF[2]; red[6][sub][rr] = aF[3];
      __syncthreads();  // B3: red ready
    }

    if (tid < 32) {
      float sI = 0.f, sU = 0.f, sO = 0.f;
      float sF0 = 0.f, sF1 = 0.f, sF2 = 0.f, sF3 = 0.f;
      if (nc > 0) {
#pragma unroll
        for (int s = 0; s < NSUB; s++) {
          sI += red[0][s][tid]; sU += red[1][s][tid]; sO += red[2][s][tid];
          sF0 += red[3][s][tid]; sF1 += red[4][s][tid];
          sF2 += red[5][s][tid]; sF3 += red[6][s][tid];
        }
      }
      const float ig = ipre + bI + sI;
      const float ug = upre + bU + sU;
      const float og = opre + bO + sO;
      float c = sigm(ig) * tanhf(ug);
      if (nc > 0) c += sigm(fpre + bF + sF0) * cC[0];
      if (nc > 1) c += sigm(fpre + bF + sF1) * cC[1];
      if (nc > 2) c += sigm(fpre + bF + sF2) * cC[2];
      if (nc > 3) c += sigm(fpre + bF + sF3) * cC[3];
      const float h = sigm(og) * tanhf(c);
      AT_ST(Hout + (size_t)j * HID + rpp, h);
      AT_ST(Cout + (size_t)j * HID + rpp, c);
    }
    // order: data stores reach the LLC before the flag store issues.
    asm volatile("" ::: "memory");
    __builtin_amdgcn_s_waitcnt(0);
    asm volatile("" ::: "memory");
    if (tid == 0)
      AT_ST(flags + j * FPN + slice, 1);
  }
}

// ---------------------------------------------------------------------------
// Workspace: [0,128MB) i2h ; [128MB, +1MB) flags (16 int32 per node)
// ---------------------------------------------------------------------------
extern "C" void kernel_launch(void* const* d_in, const int* in_sizes, int n_in,
                              void* d_out, int out_size, void* d_ws, size_t ws_size,
                              hipStream_t stream) {
  const float* inputs    = (const float*)d_in[0];
  const float* i2h_w     = (const float*)d_in[1];
  const float* i2h_b     = (const float*)d_in[2];
  const float* hs2h_w    = (const float*)d_in[3];
  const float* hs2h_b    = (const float*)d_in[4];
  const float* hc2h_w    = (const float*)d_in[5];
  const float* hc2h_b    = (const float*)d_in[6];
  const int*   child_idx = (const int*)d_in[7];
  const int*   child_mask= (const int*)d_in[8];

  float* Hout = (float*)d_out;
  float* Cout = Hout + (size_t)N_NODES * HID;

  char* ws = (char*)d_ws;
  const size_t i2h_bytes = (size_t)N_NODES * G4 * sizeof(float);
  float* i2h = (float*)ws;
  int*   flags = (int*)(ws + i2h_bytes);

  hipMemsetAsync(flags, 0, N_NODES * FPN * sizeof(int), stream);

  dim3 ggrid(G4 / 64, N_NODES / 64);
  gemm_i2h<<<ggrid, 256, 0, stream>>>(inputs, i2h_w, i2h_b, i2h);
  recur<<<NWG, BLK, 0, stream>>>(i2h, hs2h_w, hc2h_w, hs2h_b, hc2h_b,
                                 child_idx, child_mask, Hout, Cout, flags);
}